// Round 5
// baseline (297.286 us; speedup 1.0000x reference)
//
#include <hip/hip_runtime.h>
#include <hip/hip_bf16.h>
#include <math.h>

#define D 128
#define SB 512
#define GNUM 256       // edge-slice blocks for counting sort (one per CU)
#define MAXW4 12512    // u8-packed histogram words: supports N <= 50048

typedef __attribute__((ext_vector_type(8))) short bf16x8;
typedef __attribute__((ext_vector_type(4))) float f32x4;
typedef __attribute__((ext_vector_type(2))) float fv2;

__device__ __forceinline__ bf16x8 pack8(const float* r) {
    union { bf16x8 v; __hip_bfloat162 h[4]; } u;
#pragma unroll
    for (int i = 0; i < 4; ++i)
        u.h[i] = __float22bfloat162_rn(make_float2(r[2 * i], r[2 * i + 1]));
    return u.v;
}

__device__ __forceinline__ uint2 packfp8x8(const float* r) {
    unsigned int w0 = 0, w1 = 0;
    w0 = __builtin_amdgcn_cvt_pk_fp8_f32(r[0], r[1], w0, false);
    w0 = __builtin_amdgcn_cvt_pk_fp8_f32(r[2], r[3], w0, true);
    w1 = __builtin_amdgcn_cvt_pk_fp8_f32(r[4], r[5], w1, false);
    w1 = __builtin_amdgcn_cvt_pk_fp8_f32(r[6], r[7], w1, true);
    return make_uint2(w0, w1);
}

// acc[0..3] (fv2 each) += fp8x8(v)
__device__ __forceinline__ void acc_fp8x8(uint2 v, fv2* a) {
    a[0] += __builtin_amdgcn_cvt_pk_f32_fp8(v.x, false);
    a[1] += __builtin_amdgcn_cvt_pk_f32_fp8(v.x, true);
    a[2] += __builtin_amdgcn_cvt_pk_f32_fp8(v.y, false);
    a[3] += __builtin_amdgcn_cvt_pk_f32_fp8(v.y, true);
}

// acc[0..7] += w * fp8x16(v)  (gat path, full 128B rows)
__device__ __forceinline__ void acc_fp8x16w(uint4 v, float w, fv2* a) {
    fv2 wv = {w, w};
    a[0] += wv * __builtin_amdgcn_cvt_pk_f32_fp8(v.x, false);
    a[1] += wv * __builtin_amdgcn_cvt_pk_f32_fp8(v.x, true);
    a[2] += wv * __builtin_amdgcn_cvt_pk_f32_fp8(v.y, false);
    a[3] += wv * __builtin_amdgcn_cvt_pk_f32_fp8(v.y, true);
    a[4] += wv * __builtin_amdgcn_cvt_pk_f32_fp8(v.z, false);
    a[5] += wv * __builtin_amdgcn_cvt_pk_f32_fp8(v.z, true);
    a[6] += wv * __builtin_amdgcn_cvt_pk_f32_fp8(v.w, false);
    a[7] += wv * __builtin_amdgcn_cvt_pk_f32_fp8(v.w, true);
}

__device__ __forceinline__ float fast_exp2(float x) {
#if __has_builtin(__builtin_amdgcn_exp2f)
    return __builtin_amdgcn_exp2f(x);
#else
    return exp2f(x);
#endif
}

// ---------------- fused dual histogram (u8-packed, LDS, no global atomics) ----------------
__global__ __launch_bounds__(256) void histo_both(const int* __restrict__ src,
                                                  const int* __restrict__ dst,
                                                  unsigned int* __restrict__ Hs,
                                                  unsigned int* __restrict__ Hd,
                                                  int E, int N) {
    __shared__ unsigned int h[2 * MAXW4];  // 100 KB: [0,words)=src, [words,2*words)=dst
    int words = (N + 3) >> 2;
    for (int i = threadIdx.x; i < 2 * words; i += 256) h[i] = 0;
    __syncthreads();
    int per = (E + GNUM - 1) / GNUM;
    int lo = blockIdx.x * per;
    int hi = min(E, lo + per);
    for (int e = lo + (int)threadIdx.x; e < hi; e += 256) {
        int s = src[e];
        int d = dst[e];
        atomicAdd(&h[s >> 2], 1u << ((s & 3) * 8));
        atomicAdd(&h[words + (d >> 2)], 1u << ((d & 3) * 8));
    }
    __syncthreads();
    unsigned int* hsrow = Hs + (size_t)blockIdx.x * words;
    unsigned int* hdrow = Hd + (size_t)blockIdx.x * words;
    for (int i = threadIdx.x; i < words; i += 256) {
        hsrow[i] = h[i];
        hdrow[i] = h[words + i];
    }
}

// ---------------- column sum (src histogram u8 -> n2) ----------------
__global__ void col_sum8(const unsigned char* __restrict__ H, float* __restrict__ n2, int N) {
    int bin = blockIdx.x * blockDim.x + threadIdx.x;
    if (bin >= N) return;
    size_t stride = (size_t)(((N + 3) >> 2) * 4);
    unsigned int s = 0;
    for (int b = 0; b < GNUM; ++b) s += H[(size_t)b * stride + bin];
    n2[bin] = rsqrtf((float)max((int)s, 1));
}

// ---------------- column scan (dst histogram u8 -> per-block base, in place) ----------------
__global__ void col_scan8(unsigned char* __restrict__ Hd, int* __restrict__ deg_in,
                          float* __restrict__ n1, int N) {
    int bin = blockIdx.x * blockDim.x + threadIdx.x;
    if (bin >= N) return;
    size_t stride = (size_t)(((N + 3) >> 2) * 4);
    unsigned int run = 0;
    for (int b = 0; b < GNUM; ++b) {
        size_t o = (size_t)b * stride + bin;
        unsigned int hv = Hd[o];
        Hd[o] = (unsigned char)run;   // exclusive prefix within column (max ~deg < 256)
        run += hv;
    }
    deg_in[bin] = (int)run;
    n1[bin] = rsqrtf((float)max((int)run, 1));
}

// ---------------- exclusive scan (3-kernel) ----------------
__global__ void scan_blocks(const int* __restrict__ in, int* __restrict__ out,
                            int* __restrict__ sums, int n) {
    __shared__ int sh[SB];
    int gid = blockIdx.x * SB + threadIdx.x;
    int v = (gid < n) ? in[gid] : 0;
    sh[threadIdx.x] = v;
    __syncthreads();
    for (int off = 1; off < SB; off <<= 1) {
        int t = (threadIdx.x >= off) ? sh[threadIdx.x - off] : 0;
        __syncthreads();
        sh[threadIdx.x] += t;
        __syncthreads();
    }
    if (gid < n) out[gid] = sh[threadIdx.x] - v;      // exclusive
    if (threadIdx.x == SB - 1) sums[blockIdx.x] = sh[threadIdx.x];
}

__global__ void scan_sums(int* sums, int nb) {
    __shared__ int sh[SB];
    int v = (threadIdx.x < nb) ? sums[threadIdx.x] : 0;
    sh[threadIdx.x] = v;
    __syncthreads();
    for (int off = 1; off < SB; off <<= 1) {
        int t = (threadIdx.x >= off) ? sh[threadIdx.x - off] : 0;
        __syncthreads();
        sh[threadIdx.x] += t;
        __syncthreads();
    }
    if (threadIdx.x < nb) sums[threadIdx.x] = sh[threadIdx.x] - v;  // exclusive
}

__global__ void scan_add(int* out, const int* __restrict__ sums, int n, int E) {
    int gid = blockIdx.x * SB + threadIdx.x;
    if (gid < n) out[gid] += sums[blockIdx.x];
    if (blockIdx.x == 0 && threadIdx.x == 0) out[n] = E;  // row_ptr[N] = E
}

// ---------------- CSR fill via u8 LDS local ranks (no global atomics) ----------------
__global__ __launch_bounds__(256) void fill_part(const int* __restrict__ src,
                                                 const int* __restrict__ dst,
                                                 const int* __restrict__ rowp,
                                                 const unsigned char* __restrict__ base,
                                                 int* __restrict__ csr, int E, int N) {
    __shared__ unsigned int cur[MAXW4];  // 50 KB u8-packed cursors
    int words = (N + 3) >> 2;
    for (int i = threadIdx.x; i < words; i += 256) cur[i] = 0;
    __syncthreads();
    size_t stride = (size_t)(words * 4);
    int per = (E + GNUM - 1) / GNUM;
    int lo = blockIdx.x * per;
    int hi = min(E, lo + per);
    const unsigned char* brow = base + (size_t)blockIdx.x * stride;
    for (int e = lo + (int)threadIdx.x; e < hi; e += 256) {
        int d = dst[e];
        unsigned int sh = (d & 3) * 8;
        unsigned int r = atomicAdd(&cur[d >> 2], 1u << sh);
        int rank = (int)((r >> sh) & 0xFFu);
        int pos = rowp[d] + (int)brow[d] + rank;
        csr[pos] = src[e];
    }
}

// ---------------- convert: nf8 = fp8(n2 .* feats), half-split layout [2][N][64B] ----------
// Half h holds dims [64h, 64h+64); byte b of a half-row = dim 64h+b.
__global__ void convert_nf8(const float* __restrict__ feats, const float* __restrict__ n2,
                            unsigned int* __restrict__ nf8, int N) {
    int t = blockIdx.x * blockDim.x + threadIdx.x;
    int n = t >> 5, l = t & 31;
    if (n >= N) return;
    float w = n2[n];
    float4 f = *reinterpret_cast<const float4*>(feats + (size_t)n * D + l * 4);
    unsigned int w0 = 0;
    w0 = __builtin_amdgcn_cvt_pk_fp8_f32(f.x * w, f.y * w, w0, false);
    w0 = __builtin_amdgcn_cvt_pk_fp8_f32(f.z * w, f.w * w, w0, true);
    int half = l >> 4;       // dims 4l..4l+3 -> half = (4l)>>6
    int inner = l & 15;      // u32 word within the 64B half-row
    nf8[(size_t)half * N * 16 + (size_t)n * 16 + inner] = w0;
}

// ---------------- convert W -> bf16 B-fragment layout ----------------
__global__ void convert_W(const float* __restrict__ W, ushort* __restrict__ Wb) {
    int tid = blockIdx.x * blockDim.x + threadIdx.x;
    if (tid >= 2048) return;
    int c = tid >> 8, t = (tid >> 6) & 3, lane = tid & 63;
    int col = c * 16 + (lane & 15);
    int k0 = t * 32 + ((lane >> 4) << 3);
    ushort* outp = Wb + (size_t)tid * 8;
    for (int j = 0; j < 8; ++j) {
        __hip_bfloat16 b = __float2bfloat16(W[(size_t)(k0 + j) * D + col]);
        outp[j] = *reinterpret_cast<ushort*>(&b);
    }
}

// ---------------- fp8 SpMM half-pass: 8 nodes/wave, 8 lanes/node, 8B/lane (64B row) -------
// Table layout [2][N][64B]; HALF selects dims [64*HALF, 64*HALF+64). One cache line
// per edge; the 3.2 MB half-table fits per-XCD L2 -> gathers become L2 hits.
// g = lane>>3 (node slot), c = lane&7 (dims 64*HALF + [c*8, c*8+8)).
// MODE 0 (rst):  gather nf8 -> t = fp8(n1[wid]^2 * sum)
// MODE 1 (hop1): x = n2*sum ; yp = bf16(x)       ; t = fp8(n1*x)
// MODE 2 (hop2): x = n2*sum ; yp += x            ; t = fp8(n1*x)
// MODE 3 (fin):  x3 = n2*sum ; y = bf16(0.25*(feats + yp + x3))
template <int MODE, int HALF>
__global__ __launch_bounds__(256) void spmmh(const unsigned char* __restrict__ xs,
                                             const ushort* __restrict__ ypin,
                                             const float* __restrict__ feats,
                                             const int* __restrict__ rowp,
                                             const int* __restrict__ csr,
                                             const float* __restrict__ n1,
                                             const float* __restrict__ n2,
                                             ushort* __restrict__ yp,
                                             unsigned char* __restrict__ outs, int N) {
    int lane = threadIdx.x & 63;
    int g = lane >> 3, c = lane & 7;
    int wid = ((blockIdx.x * blockDim.x + threadIdx.x) >> 6) * 8 + g;
    if (wid >= N) return;
    int beg = rowp[wid], end = rowp[wid + 1];
    const unsigned char* xb = xs + (size_t)HALF * N * 64;
    unsigned coff = (unsigned)(c << 3);
    fv2 acc2[4] = {{0.f, 0.f}, {0.f, 0.f}, {0.f, 0.f}, {0.f, 0.f}};
    int base = beg;
    int cur_s = (beg < end) ? csr[beg + min(c, end - beg - 1)] : 0;
    while (base < end) {
        int nb = base + 8;
        int next_s = 0;
        if (nb < end) next_s = csr[nb + min(c, end - nb - 1)];  // prefetch next chunk
        int kn = min(8, end - base);
        uint2 v[8];
#pragma unroll
        for (int k = 0; k < 8; ++k) {
            int sk = __shfl(cur_s, k, 8);
            if (k < kn) v[k] = *(const uint2*)(xb + ((((unsigned)sk) << 6) | coff));
        }
#pragma unroll
        for (int k = 0; k < 8; ++k)
            if (k < kn) acc_fp8x8(v[k], acc2);
        cur_s = next_s;
        base = nb;
    }
    float acc[8];
#pragma unroll
    for (int j = 0; j < 4; ++j) {
        acc[2 * j] = acc2[j][0];
        acc[2 * j + 1] = acc2[j][1];
    }
    if (MODE == 0) {
        float s1 = n1[wid];
        float sc = s1 * s1;
        float r[8];
#pragma unroll
        for (int i = 0; i < 8; ++i) r[i] = acc[i] * sc;
        *reinterpret_cast<uint2*>(outs + (size_t)HALF * N * 64 + (size_t)wid * 64 + coff) =
            packfp8x8(r);
    } else if (MODE == 1 || MODE == 2) {
        float sp = n2[wid];
        float ss = sp * n1[wid];
        float xv[8], rs[8];
#pragma unroll
        for (int i = 0; i < 8; ++i) { xv[i] = acc[i] * sp; rs[i] = acc[i] * ss; }
        if (MODE == 2) {
            bf16x8 prev = *reinterpret_cast<const bf16x8*>(
                ypin + (size_t)wid * 128 + HALF * 64 + c * 8);
            const __hip_bfloat162* h2 = reinterpret_cast<const __hip_bfloat162*>(&prev);
#pragma unroll
            for (int i = 0; i < 4; ++i) {
                float2 v2 = __bfloat1622float2(h2[i]);
                xv[2 * i] += v2.x;
                xv[2 * i + 1] += v2.y;
            }
        }
        *reinterpret_cast<bf16x8*>(yp + (size_t)wid * 128 + HALF * 64 + c * 8) = pack8(xv);
        *reinterpret_cast<uint2*>(outs + (size_t)HALF * N * 64 + (size_t)wid * 64 + coff) =
            packfp8x8(rs);
    } else {
        float sp = n2[wid];
        float4 f0 = *reinterpret_cast<const float4*>(feats + (size_t)wid * D + HALF * 64 + c * 8);
        float4 f1 = *reinterpret_cast<const float4*>(feats + (size_t)wid * D + HALF * 64 + c * 8 + 4);
        float ft[8] = {f0.x, f0.y, f0.z, f0.w, f1.x, f1.y, f1.z, f1.w};
        bf16x8 prev = *reinterpret_cast<const bf16x8*>(
            ypin + (size_t)wid * 128 + HALF * 64 + c * 8);
        const __hip_bfloat162* h2 = reinterpret_cast<const __hip_bfloat162*>(&prev);
        float r[8];
#pragma unroll
        for (int i = 0; i < 4; ++i) {
            float2 v2 = __bfloat1622float2(h2[i]);
            r[2 * i]     = 0.25f * (ft[2 * i] + v2.x + acc[2 * i] * sp);
            r[2 * i + 1] = 0.25f * (ft[2 * i + 1] + v2.y + acc[2 * i + 1] * sp);
        }
        *reinterpret_cast<bf16x8*>(yp + (size_t)wid * 128 + HALF * 64 + c * 8) = pack8(r);
    }
}

// ---------------- GAT, 8 nodes/wave, 8 lanes/node over fp8 h (16B/lane, full rows) --------
// (unchanged control: full 128B rows, [N][128] permuted layout from gemm_mfma)
// Distributed attention weights: lane c computes p for edge c of each chunk; weights
// broadcast via width-8 shfl. Softmax denominator via width-8 reduce at the end.
// acc f[j] -> dim 16j+2c, f[j+8] -> dim 16j+2c+1.
__global__ __launch_bounds__(256) void gatw(const uint4* __restrict__ h16,
                                            const int* __restrict__ rowp,
                                            const int* __restrict__ csr,
                                            const float2* __restrict__ elsc,
                                            const float* __restrict__ er,
                                            const float* __restrict__ bias,
                                            float* __restrict__ out, int N) {
    int lane = threadIdx.x & 63;
    int g = lane >> 3, c = lane & 7;
    int wid = ((blockIdx.x * blockDim.x + threadIdx.x) >> 6) * 8 + g;
    if (wid >= N) return;
    int beg = rowp[wid], end = rowp[wid + 1];
    int cnt = end - beg;
    int nfull = cnt >> 3;
    int rem = cnt & 7;
    const char* xb = (const char*)h16;
    unsigned coff = (unsigned)(c << 4);
    const int* cp = csr + beg + c;
    float ern = er[wid];
    float psum = 0.f;
    fv2 acc2[8] = {{0.f, 0.f}, {0.f, 0.f}, {0.f, 0.f}, {0.f, 0.f},
                   {0.f, 0.f}, {0.f, 0.f}, {0.f, 0.f}, {0.f, 0.f}};
    int base = beg;
    int cur_s = (beg < end) ? csr[beg + min(c, end - beg - 1)] : 0;
    while (base < end) {
        int nb = base + 8;
        int next_s = 0;
        if (nb < end) next_s = csr[nb + min(c, end - nb - 1)];  // prefetch next chunk
        int kn = min(8, end - base);
        float2 es = elsc[cur_s];
        float t = es.x + ern;
        t = fmaxf(t, 0.2f * t);                 // leaky_relu (slope commutes with log2e)
        float p = (c < kn) ? fast_exp2(t) : 0.f;
        psum += p;
        float wv = p * es.y;                    // fold fp8 row scale into the weight
        uint4 v[8];
#pragma unroll
        for (int k = 0; k < 8; ++k) {
            int sk = __shfl(cur_s, k, 8);
            if (k < kn) v[k] = *(const uint4*)(xb + ((((unsigned)sk) << 7) | coff));
        }
#pragma unroll
        for (int k = 0; k < 8; ++k)
            if (k < kn) {
                float wk = __shfl(wv, k, 8);
                acc_fp8x16w(v[k], wk, acc2);
            }
        cur_s = next_s;
        base = nb;
    }
    (void)nfull; (void)rem; (void)cp;
    // reduce softmax denominator across the 8 lanes of the group
    psum += __shfl_xor(psum, 1, 8);
    psum += __shfl_xor(psum, 2, 8);
    psum += __shfl_xor(psum, 4, 8);
    float inv = psum > 0.f ? 1.f / psum : 0.f;
    float zA[8], zB[8];
    float mx = -INFINITY;
#pragma unroll
    for (int j = 0; j < 8; ++j) {
        float2 b2 = *reinterpret_cast<const float2*>(bias + 16 * j + 2 * c);
        zA[j] = fmaxf(acc2[j >> 1][j & 1] * inv + b2.x, 0.f);               // f[j]
        zB[j] = fmaxf(acc2[(j + 8) >> 1][(j + 8) & 1] * inv + b2.y, 0.f);   // f[j+8]
        mx = fmaxf(mx, fmaxf(zA[j], zB[j]));
    }
    mx = fmaxf(mx, __shfl_xor(mx, 1, 8));
    mx = fmaxf(mx, __shfl_xor(mx, 2, 8));
    mx = fmaxf(mx, __shfl_xor(mx, 4, 8));
    float pz = 0.f;
#pragma unroll
    for (int j = 0; j < 8; ++j) pz += __expf(zA[j] - mx) + __expf(zB[j] - mx);
    pz += __shfl_xor(pz, 1, 8);
    pz += __shfl_xor(pz, 2, 8);
    pz += __shfl_xor(pz, 4, 8);
    float ls = logf(pz);
    float* op = out + (size_t)wid * D;
#pragma unroll
    for (int j = 0; j < 8; ++j) {
        float2 o2 = make_float2(zA[j] - mx - ls, zB[j] - mx - ls);
        *reinterpret_cast<float2*>(op + 16 * j + 2 * c) = o2;
    }
}

// ---------------- MFMA GEMM: h = y @ W (-> per-row-scaled fp8), el/er (log2e-scaled) --------
// h8 row layout (permuted): byte j of a row holds dim (j&7)*16 + (j>>3).
// elsc[row] = { el[row]*log2(e), rowmax/448 } ; er[row] *= log2(e).
__global__ __launch_bounds__(256) void gemm_mfma(const ushort* __restrict__ ybf,
                                                 const ushort* __restrict__ Wb,
                                                 const float* __restrict__ attnl,
                                                 const float* __restrict__ attnr,
                                                 unsigned char* __restrict__ h8,
                                                 float2* __restrict__ elsc,
                                                 float* __restrict__ er, int N) {
    __shared__ ushort Ws[16384];  // 32 KB packed W
    {
        const float4* srcv = reinterpret_cast<const float4*>(Wb);
        float4* dstv = reinterpret_cast<float4*>(Ws);
        for (int i = threadIdx.x; i < 2048; i += 256) dstv[i] = srcv[i];
    }
    __syncthreads();
    int wave = threadIdx.x >> 6, lane = threadIdx.x & 63;
    int base = blockIdx.x * 64 + wave * 16;
    if (base >= N) return;
    int col16 = lane & 15, rgrp = lane >> 4;

    int arow = base + col16;
    const bf16x8* yrow = reinterpret_cast<const bf16x8*>(ybf + (size_t)arow * 128);
    bf16x8 afrag[4];
#pragma unroll
    for (int t = 0; t < 4; ++t) afrag[t] = yrow[t * 4 + rgrp];

    const bf16x8* WsV = reinterpret_cast<const bf16x8*>(Ws);
    f32x4 acc[8];
#pragma unroll
    for (int c = 0; c < 8; ++c) acc[c] = (f32x4){0.f, 0.f, 0.f, 0.f};
#pragma unroll
    for (int c = 0; c < 8; ++c) {
#pragma unroll
        for (int t = 0; t < 4; ++t) {
            bf16x8 b = WsV[(c * 4 + t) * 64 + lane];
            acc[c] = __builtin_amdgcn_mfma_f32_16x16x32_bf16(afrag[t], b, acc[c], 0, 0, 0);
        }
    }

    float pl[4] = {0.f, 0.f, 0.f, 0.f}, pr[4] = {0.f, 0.f, 0.f, 0.f};
#pragma unroll
    for (int c = 0; c < 8; ++c) {
        float alc = attnl[c * 16 + col16];
        float arc = attnr[c * 16 + col16];
#pragma unroll
        for (int r = 0; r < 4; ++r) {
            pl[r] += acc[c][r] * alc;
            pr[r] += acc[c][r] * arc;
        }
    }
#pragma unroll
    for (int r = 0; r < 4; ++r) {
#pragma unroll
        for (int off = 8; off; off >>= 1) {
            pl[r] += __shfl_xor(pl[r], off);
            pr[r] += __shfl_xor(pr[r], off);
        }
    }

    // per-row absmax over the 16x128 tile rows (local 8 + butterfly over 16 lanes)
    float rmax[4];
#pragma unroll
    for (int r = 0; r < 4; ++r) {
        float m = 0.f;
#pragma unroll
        for (int c = 0; c < 8; ++c) m = fmaxf(m, fabsf(acc[c][r]));
#pragma unroll
        for (int off = 1; off < 16; off <<= 1) m = fmaxf(m, __shfl_xor(m, off));
        rmax[r] = fmaxf(m, 1e-20f);
    }

    // quantize: 8B chunk per lane per row (contiguous in the permuted layout)
#pragma unroll
    for (int r = 0; r < 4; ++r) {
        float iv = 448.f / rmax[r];
        float rr[8];
#pragma unroll
        for (int c = 0; c < 8; ++c) rr[c] = acc[c][r] * iv;
        uint2 pk = packfp8x8(rr);
        int row = base + rgrp * 4 + r;
        *reinterpret_cast<uint2*>(h8 + (size_t)row * 128 + col16 * 8) = pk;
    }

    const float LOG2E = 1.44269504088896340736f;
    if (col16 == 0) {
#pragma unroll
        for (int r = 0; r < 4; ++r) {
            int row = base + rgrp * 4 + r;
            elsc[row] = make_float2(pl[r] * LOG2E, rmax[r] * (1.f / 448.f));
            er[row] = pr[r] * LOG2E;
        }
    }
}

extern "C" void kernel_launch(void* const* d_in, const int* in_sizes, int n_in,
                              void* d_out, int out_size, void* d_ws, size_t ws_size,
                              hipStream_t stream) {
    const float* feats  = (const float*)d_in[0];
    const float* W      = (const float*)d_in[1];
    const float* attn_l = (const float*)d_in[2];
    const float* attn_r = (const float*)d_in[3];
    const float* bias   = (const float*)d_in[4];
    const int*   src    = (const int*)d_in[5];
    const int*   dst    = (const int*)d_in[6];
    int N = in_sizes[0] / D;
    int E = in_sizes[5];
    float* out = (float*)d_out;

    char* p = (char*)d_ws;
    auto alloc = [&](size_t bytes) {
        char* r = p;
        p += (bytes + 255) & ~size_t(255);
        return r;
    };
    int*    deg_in = (int*)alloc((size_t)N * 4);
    int*    rowp   = (int*)alloc(((size_t)N + 1) * 4);
    int*    bsums  = (int*)alloc((size_t)SB * 4);
    float*  n1     = (float*)alloc((size_t)N * 4);
    float*  n2     = (float*)alloc((size_t)N * 4);
    float*  er     = (float*)alloc((size_t)N * 4);
    float2* elsc   = (float2*)alloc((size_t)N * 8);
    int*    csr    = (int*)alloc((size_t)E * 4);
    ushort* Wb     = (ushort*)alloc((size_t)16384 * 2);
    // bf16 [N][128] buffers (12.8 MB each), allocated back-to-back so they can
    // alias the 2 x (GNUM x N-byte) u8 histograms (dead before first bf16 use)
    ushort* bufY1  = (ushort*)alloc((size_t)N * 128 * 2);  // Hs8 | yp (x1, x1+x2)
    ushort* bufY   = (ushort*)alloc((size_t)N * 128 * 2);  // Hd8 | y
    // fp8 [2][N][64] tables (6.4 MB each)
    unsigned char* t0 = (unsigned char*)alloc((size_t)N * 128);  // x0s8, then h8 (gemm, [N][128])
    unsigned char* t1 = (unsigned char*)alloc((size_t)N * 128);  // nf8, then x1s8
    unsigned char* t2 = (unsigned char*)alloc((size_t)N * 128);  // x2s8
    unsigned int* Hs = (unsigned int*)bufY1;
    unsigned int* Hd = (unsigned int*)bufY;

    const int tb = 256;
    // CSR build: fused dual histo -> n2 / base+deg+n1 -> row scan -> fill
    histo_both<<<GNUM, tb, 0, stream>>>(src, dst, Hs, Hd, E, N);
    col_sum8<<<(N + tb - 1) / tb, tb, 0, stream>>>((const unsigned char*)Hs, n2, N);
    col_scan8<<<(N + tb - 1) / tb, tb, 0, stream>>>((unsigned char*)Hd, deg_in, n1, N);
    int nb = (N + SB - 1) / SB;
    scan_blocks<<<nb, SB, 0, stream>>>(deg_in, rowp, bsums, N);
    scan_sums<<<1, SB, 0, stream>>>(bsums, nb);
    scan_add<<<nb, SB, 0, stream>>>(rowp, bsums, N, E);
    fill_part<<<GNUM, tb, 0, stream>>>(src, dst, rowp, (const unsigned char*)Hd, csr, E, N);
    convert_W<<<8, tb, 0, stream>>>(W, Wb);
    convert_nf8<<<((size_t)N * 32 + tb - 1) / tb, tb, 0, stream>>>(feats, n2,
                                                                   (unsigned int*)t1, N);

    int wgrid8 = (N + 31) / 32;  // 4 waves/block x 8 nodes/wave = 32 nodes/block
    // rst: gather nf8(t1) -> x0s8(t0), dim-halves sequential (each half-table L2-resident)
    spmmh<0, 0><<<wgrid8, 256, 0, stream>>>(t1, nullptr, nullptr, rowp, csr, n1, n2,
                                            nullptr, t0, N);
    spmmh<0, 1><<<wgrid8, 256, 0, stream>>>(t1, nullptr, nullptr, rowp, csr, n1, n2,
                                            nullptr, t0, N);
    // hop1: gather t0 -> yp=x1 (bufY1), x1s8(t1)
    spmmh<1, 0><<<wgrid8, 256, 0, stream>>>(t0, nullptr, nullptr, rowp, csr, n1, n2,
                                            bufY1, t1, N);
    spmmh<1, 1><<<wgrid8, 256, 0, stream>>>(t0, nullptr, nullptr, rowp, csr, n1, n2,
                                            bufY1, t1, N);
    // hop2: gather t1 -> yp+=x2, x2s8(t2)
    spmmh<2, 0><<<wgrid8, 256, 0, stream>>>(t1, bufY1, nullptr, rowp, csr, n1, n2,
                                            bufY1, t2, N);
    spmmh<2, 1><<<wgrid8, 256, 0, stream>>>(t1, bufY1, nullptr, rowp, csr, n1, n2,
                                            bufY1, t2, N);
    // fin: gather t2 -> y = 0.25*(feats + yp + x3) -> bufY
    spmmh<3, 0><<<wgrid8, 256, 0, stream>>>(t2, bufY1, feats, rowp, csr, n1, n2,
                                            bufY, nullptr, N);
    spmmh<3, 1><<<wgrid8, 256, 0, stream>>>(t2, bufY1, feats, rowp, csr, n1, n2,
                                            bufY, nullptr, N);

    // h -> per-row-scaled fp8 into t0 (dead after hop1); el/er pre-scaled by log2(e)
    gemm_mfma<<<(N + 63) / 64, 256, 0, stream>>>(bufY, Wb, attn_l, attn_r,
                                                 (unsigned char*)t0, elsc, er, N);
    gatw<<<wgrid8, 256, 0, stream>>>((const uint4*)t0, rowp, csr, elsc, er, bias, out, N);
}

// Round 6
// 258.695 us; speedup vs baseline: 1.1492x; 1.1492x over previous
//
#include <hip/hip_runtime.h>
#include <hip/hip_bf16.h>
#include <math.h>

#define D 128
#define SB 512
#define GNUM 256       // edge-slice blocks for counting sort (one per CU)
#define MAXW4 12512    // u8-packed histogram words: supports N <= 50048

typedef __attribute__((ext_vector_type(8))) short bf16x8;
typedef __attribute__((ext_vector_type(4))) float f32x4;
typedef __attribute__((ext_vector_type(2))) float fv2;

__device__ __forceinline__ bf16x8 pack8(const float* r) {
    union { bf16x8 v; __hip_bfloat162 h[4]; } u;
#pragma unroll
    for (int i = 0; i < 4; ++i)
        u.h[i] = __float22bfloat162_rn(make_float2(r[2 * i], r[2 * i + 1]));
    return u.v;
}

__device__ __forceinline__ uint2 packfp8x8(const float* r) {
    unsigned int w0 = 0, w1 = 0;
    w0 = __builtin_amdgcn_cvt_pk_fp8_f32(r[0], r[1], w0, false);
    w0 = __builtin_amdgcn_cvt_pk_fp8_f32(r[2], r[3], w0, true);
    w1 = __builtin_amdgcn_cvt_pk_fp8_f32(r[4], r[5], w1, false);
    w1 = __builtin_amdgcn_cvt_pk_fp8_f32(r[6], r[7], w1, true);
    return make_uint2(w0, w1);
}

__device__ __forceinline__ uint4 packfp8x16(const float* r) {
    uint4 o;
    unsigned int w;
    w = 0;
    w = __builtin_amdgcn_cvt_pk_fp8_f32(r[0], r[1], w, false);
    w = __builtin_amdgcn_cvt_pk_fp8_f32(r[2], r[3], w, true);
    o.x = w;
    w = 0;
    w = __builtin_amdgcn_cvt_pk_fp8_f32(r[4], r[5], w, false);
    w = __builtin_amdgcn_cvt_pk_fp8_f32(r[6], r[7], w, true);
    o.y = w;
    w = 0;
    w = __builtin_amdgcn_cvt_pk_fp8_f32(r[8], r[9], w, false);
    w = __builtin_amdgcn_cvt_pk_fp8_f32(r[10], r[11], w, true);
    o.z = w;
    w = 0;
    w = __builtin_amdgcn_cvt_pk_fp8_f32(r[12], r[13], w, false);
    w = __builtin_amdgcn_cvt_pk_fp8_f32(r[14], r[15], w, true);
    o.w = w;
    return o;
}

// acc[0..7] (fv2 each) += fp8x16(v)
__device__ __forceinline__ void acc_fp8x16(uint4 v, fv2* a) {
    a[0] += __builtin_amdgcn_cvt_pk_f32_fp8(v.x, false);
    a[1] += __builtin_amdgcn_cvt_pk_f32_fp8(v.x, true);
    a[2] += __builtin_amdgcn_cvt_pk_f32_fp8(v.y, false);
    a[3] += __builtin_amdgcn_cvt_pk_f32_fp8(v.y, true);
    a[4] += __builtin_amdgcn_cvt_pk_f32_fp8(v.z, false);
    a[5] += __builtin_amdgcn_cvt_pk_f32_fp8(v.z, true);
    a[6] += __builtin_amdgcn_cvt_pk_f32_fp8(v.w, false);
    a[7] += __builtin_amdgcn_cvt_pk_f32_fp8(v.w, true);
}

// acc[0..7] += w * fp8x16(v)
__device__ __forceinline__ void acc_fp8x16w(uint4 v, float w, fv2* a) {
    fv2 wv = {w, w};
    a[0] += wv * __builtin_amdgcn_cvt_pk_f32_fp8(v.x, false);
    a[1] += wv * __builtin_amdgcn_cvt_pk_f32_fp8(v.x, true);
    a[2] += wv * __builtin_amdgcn_cvt_pk_f32_fp8(v.y, false);
    a[3] += wv * __builtin_amdgcn_cvt_pk_f32_fp8(v.y, true);
    a[4] += wv * __builtin_amdgcn_cvt_pk_f32_fp8(v.z, false);
    a[5] += wv * __builtin_amdgcn_cvt_pk_f32_fp8(v.z, true);
    a[6] += wv * __builtin_amdgcn_cvt_pk_f32_fp8(v.w, false);
    a[7] += wv * __builtin_amdgcn_cvt_pk_f32_fp8(v.w, true);
}

__device__ __forceinline__ float fast_exp2(float x) {
#if __has_builtin(__builtin_amdgcn_exp2f)
    return __builtin_amdgcn_exp2f(x);
#else
    return exp2f(x);
#endif
}

// ---------------- fused dual histogram (u8-packed, LDS, no global atomics) ----------------
__global__ __launch_bounds__(256) void histo_both(const int* __restrict__ src,
                                                  const int* __restrict__ dst,
                                                  unsigned int* __restrict__ Hs,
                                                  unsigned int* __restrict__ Hd,
                                                  int* __restrict__ bins32,
                                                  int E, int N) {
    if (blockIdx.x == 0 && threadIdx.x < 32) bins32[threadIdx.x] = 0;
    __shared__ unsigned int h[2 * MAXW4];  // 100 KB: [0,words)=src, [words,2*words)=dst
    int words = (N + 3) >> 2;
    for (int i = threadIdx.x; i < 2 * words; i += 256) h[i] = 0;
    __syncthreads();
    int per = (E + GNUM - 1) / GNUM;
    int lo = blockIdx.x * per;
    int hi = min(E, lo + per);
    for (int e = lo + (int)threadIdx.x; e < hi; e += 256) {
        int s = src[e];
        int d = dst[e];
        atomicAdd(&h[s >> 2], 1u << ((s & 3) * 8));
        atomicAdd(&h[words + (d >> 2)], 1u << ((d & 3) * 8));
    }
    __syncthreads();
    unsigned int* hsrow = Hs + (size_t)blockIdx.x * words;
    unsigned int* hdrow = Hd + (size_t)blockIdx.x * words;
    for (int i = threadIdx.x; i < words; i += 256) {
        hsrow[i] = h[i];
        hdrow[i] = h[words + i];
    }
}

// ---------------- fused column sum (Hs -> n2) + column scan (Hd -> bases, deg, n1)
// + degree-bin (chunk-count) histogram for load-balanced node ordering ----------------
__global__ __launch_bounds__(256) void col_both(const unsigned char* __restrict__ Hs,
                                                unsigned char* __restrict__ Hd,
                                                int* __restrict__ deg_in,
                                                float* __restrict__ n1,
                                                float* __restrict__ n2,
                                                int* __restrict__ bins32,
                                                int* __restrict__ blkbase, int N) {
    __shared__ unsigned int lb[32];
    if (threadIdx.x < 32) lb[threadIdx.x] = 0;
    __syncthreads();
    int bin = blockIdx.x * 256 + threadIdx.x;
    if (bin < N) {
        size_t stride = (size_t)(((N + 3) >> 2) * 4);
        unsigned int s = 0, run = 0;
        for (int b = 0; b < GNUM; ++b) {
            size_t o = (size_t)b * stride + bin;
            s += Hs[o];
            unsigned int hv = Hd[o];
            Hd[o] = (unsigned char)run;   // exclusive prefix within column
            run += hv;
        }
        n2[bin] = rsqrtf((float)max((int)s, 1));
        deg_in[bin] = (int)run;
        n1[bin] = rsqrtf((float)max((int)run, 1));
        int cc = min(31, (int)((run + 7) >> 3));
        atomicAdd(&lb[cc], 1u);
    }
    __syncthreads();
    if (threadIdx.x < 32) {
        unsigned int cnt = lb[threadIdx.x];
        int base = 0;
        if (cnt) base = atomicAdd(&bins32[threadIdx.x], (int)cnt);
        blkbase[blockIdx.x * 32 + threadIdx.x] = base;
    }
}

// exclusive scan of the 32 degree-bin totals (single wave)
__global__ void scan32k(int* __restrict__ bins32) {
    int t = threadIdx.x;
    int orig = (t < 32) ? bins32[t] : 0;
    int v = orig;
    for (int off = 1; off < 32; off <<= 1) {
        int u = __shfl_up(v, off, 32);
        if ((t & 31) >= off) v += u;
    }
    if (t < 32) bins32[t] = v - orig;  // exclusive
}

// scatter nodes into perm, grouped by chunk-count bin (same block partition as col_both)
__global__ __launch_bounds__(256) void scatter_perm(const int* __restrict__ deg_in,
                                                    const int* __restrict__ bins32,
                                                    const int* __restrict__ blkbase,
                                                    int* __restrict__ perm, int N) {
    __shared__ unsigned int lb[32];
    if (threadIdx.x < 32) lb[threadIdx.x] = 0;
    __syncthreads();
    int node = blockIdx.x * 256 + threadIdx.x;
    if (node < N) {
        int cc = min(31, (deg_in[node] + 7) >> 3);
        unsigned int r = atomicAdd(&lb[cc], 1u);
        int pos = bins32[cc] + blkbase[blockIdx.x * 32 + cc] + (int)r;
        perm[pos] = node;
    }
}

// ---------------- exclusive scan (3-kernel) ----------------
__global__ void scan_blocks(const int* __restrict__ in, int* __restrict__ out,
                            int* __restrict__ sums, int n) {
    __shared__ int sh[SB];
    int gid = blockIdx.x * SB + threadIdx.x;
    int v = (gid < n) ? in[gid] : 0;
    sh[threadIdx.x] = v;
    __syncthreads();
    for (int off = 1; off < SB; off <<= 1) {
        int t = (threadIdx.x >= off) ? sh[threadIdx.x - off] : 0;
        __syncthreads();
        sh[threadIdx.x] += t;
        __syncthreads();
    }
    if (gid < n) out[gid] = sh[threadIdx.x] - v;      // exclusive
    if (threadIdx.x == SB - 1) sums[blockIdx.x] = sh[threadIdx.x];
}

__global__ void scan_sums(int* sums, int nb) {
    __shared__ int sh[SB];
    int v = (threadIdx.x < nb) ? sums[threadIdx.x] : 0;
    sh[threadIdx.x] = v;
    __syncthreads();
    for (int off = 1; off < SB; off <<= 1) {
        int t = (threadIdx.x >= off) ? sh[threadIdx.x - off] : 0;
        __syncthreads();
        sh[threadIdx.x] += t;
        __syncthreads();
    }
    if (threadIdx.x < nb) sums[threadIdx.x] = sh[threadIdx.x] - v;  // exclusive
}

__global__ void scan_add(int* out, const int* __restrict__ sums, int n, int E) {
    int gid = blockIdx.x * SB + threadIdx.x;
    if (gid < n) out[gid] += sums[blockIdx.x];
    if (blockIdx.x == 0 && threadIdx.x == 0) out[n] = E;  // row_ptr[N] = E
}

// ---------------- CSR fill via u8 LDS local ranks (no global atomics) ----------------
__global__ __launch_bounds__(256) void fill_part(const int* __restrict__ src,
                                                 const int* __restrict__ dst,
                                                 const int* __restrict__ rowp,
                                                 const unsigned char* __restrict__ base,
                                                 int* __restrict__ csr, int E, int N) {
    __shared__ unsigned int cur[MAXW4];  // 50 KB u8-packed cursors
    int words = (N + 3) >> 2;
    for (int i = threadIdx.x; i < words; i += 256) cur[i] = 0;
    __syncthreads();
    size_t stride = (size_t)(words * 4);
    int per = (E + GNUM - 1) / GNUM;
    int lo = blockIdx.x * per;
    int hi = min(E, lo + per);
    const unsigned char* brow = base + (size_t)blockIdx.x * stride;
    for (int e = lo + (int)threadIdx.x; e < hi; e += 256) {
        int d = dst[e];
        unsigned int sh = (d & 3) * 8;
        unsigned int r = atomicAdd(&cur[d >> 2], 1u << sh);
        int rank = (int)((r >> sh) & 0xFFu);
        int pos = rowp[d] + (int)brow[d] + rank;
        csr[pos] = src[e];
    }
}

// ---------------- convert: nf8 = fp8(n2 .* feats), row-major [N][128] fp8 ----------------
__global__ void convert_nf8(const float* __restrict__ feats, const float* __restrict__ n2,
                            unsigned int* __restrict__ nf8, int N) {
    int t = blockIdx.x * blockDim.x + threadIdx.x;
    int n = t >> 5, l = t & 31;
    if (n >= N) return;
    float w = n2[n];
    float4 f = *reinterpret_cast<const float4*>(feats + (size_t)n * D + l * 4);
    unsigned int w0 = 0;
    w0 = __builtin_amdgcn_cvt_pk_fp8_f32(f.x * w, f.y * w, w0, false);
    w0 = __builtin_amdgcn_cvt_pk_fp8_f32(f.z * w, f.w * w, w0, true);
    nf8[(size_t)n * 32 + l] = w0;
}

// ---------------- convert W -> bf16 B-fragment layout ----------------
__global__ void convert_W(const float* __restrict__ W, ushort* __restrict__ Wb) {
    int tid = blockIdx.x * blockDim.x + threadIdx.x;
    if (tid >= 2048) return;
    int c = tid >> 8, t = (tid >> 6) & 3, lane = tid & 63;
    int col = c * 16 + (lane & 15);
    int k0 = t * 32 + ((lane >> 4) << 3);
    ushort* outp = Wb + (size_t)tid * 8;
    for (int j = 0; j < 8; ++j) {
        __hip_bfloat16 b = __float2bfloat16(W[(size_t)(k0 + j) * D + col]);
        outp[j] = *reinterpret_cast<ushort*>(&b);
    }
}

// ---------------- fp8 SpMM, 8 independent nodes per wave, 8 lanes/node (16B/lane) ---------
// Nodes are taken in degree-binned order via perm[] so the 8 groups in a wave have
// similar chunk counts (removes max-of-8 idle inflation).
// g = lane>>3 (node slot), c = lane&7 (dims [c*16, c*16+16), natural order).
// MODE 0 (rst):  gather nf8 -> t = fp8(n1[wid]^2 * sum)
// MODE 1 (hop1): x = n2*sum ; yp = bf16(x)       ; t = fp8(n1*x)
// MODE 2 (hop2): x = n2*sum ; yp += x            ; t = fp8(n1*x)
// MODE 3 (fin):  x3 = n2*sum ; y = bf16(0.25*(feats + yp + x3))
template <int MODE>
__global__ __launch_bounds__(256) void spmmw(const uint4* __restrict__ xs16,
                                             const ushort* __restrict__ ypin,
                                             const float* __restrict__ feats,
                                             const int* __restrict__ rowp,
                                             const int* __restrict__ csr,
                                             const int* __restrict__ perm,
                                             const float* __restrict__ n1,
                                             const float* __restrict__ n2,
                                             ushort* __restrict__ yp,
                                             uint4* __restrict__ outs16, int N) {
    int lane = threadIdx.x & 63;
    int g = lane >> 3, c = lane & 7;
    int widx = ((blockIdx.x * blockDim.x + threadIdx.x) >> 6) * 8 + g;
    if (widx >= N) return;
    int wid = perm[widx];
    int beg = rowp[wid], end = rowp[wid + 1];
    fv2 acc2[8] = {{0.f, 0.f}, {0.f, 0.f}, {0.f, 0.f}, {0.f, 0.f},
                   {0.f, 0.f}, {0.f, 0.f}, {0.f, 0.f}, {0.f, 0.f}};
    int base = beg;
    int cur_s = (beg < end) ? csr[beg + min(c, end - beg - 1)] : 0;
    while (base < end) {
        int nb = base + 8;
        int next_s = 0;
        if (nb < end) next_s = csr[nb + min(c, end - nb - 1)];  // prefetch next chunk
        int kn = min(8, end - base);
        uint4 v[8];
#pragma unroll
        for (int k = 0; k < 8; ++k) {
            int sk = __shfl(cur_s, k, 8);
            if (k < kn) v[k] = xs16[(size_t)sk * 8 + c];
        }
#pragma unroll
        for (int k = 0; k < 8; ++k)
            if (k < kn) acc_fp8x16(v[k], acc2);
        cur_s = next_s;
        base = nb;
    }
    float acc[16];
#pragma unroll
    for (int j = 0; j < 8; ++j) {
        acc[2 * j] = acc2[j][0];
        acc[2 * j + 1] = acc2[j][1];
    }
    if (MODE == 0) {
        float s1 = n1[wid];
        float sc = s1 * s1;
        float r[16];
#pragma unroll
        for (int i = 0; i < 16; ++i) r[i] = acc[i] * sc;
        outs16[(size_t)wid * 8 + c] = packfp8x16(r);
    } else if (MODE == 1 || MODE == 2) {
        float sp = n2[wid];
        float ss = sp * n1[wid];
        float xv[16], rs[16];
#pragma unroll
        for (int i = 0; i < 16; ++i) { xv[i] = acc[i] * sp; rs[i] = acc[i] * ss; }
        if (MODE == 2) {
            const bf16x8* pv = reinterpret_cast<const bf16x8*>(ypin + (size_t)wid * 128 + c * 16);
#pragma unroll
            for (int hb = 0; hb < 2; ++hb) {
                bf16x8 prev = pv[hb];
                const __hip_bfloat162* h2 = reinterpret_cast<const __hip_bfloat162*>(&prev);
#pragma unroll
                for (int i = 0; i < 4; ++i) {
                    float2 v2 = __bfloat1622float2(h2[i]);
                    xv[8 * hb + 2 * i] += v2.x;
                    xv[8 * hb + 2 * i + 1] += v2.y;
                }
            }
        }
        bf16x8* ov = reinterpret_cast<bf16x8*>(yp + (size_t)wid * 128 + c * 16);
        ov[0] = pack8(xv);
        ov[1] = pack8(xv + 8);
        outs16[(size_t)wid * 8 + c] = packfp8x16(rs);
    } else {
        float sp = n2[wid];
        float ft[16];
#pragma unroll
        for (int q4 = 0; q4 < 4; ++q4) {
            float4 f = *reinterpret_cast<const float4*>(feats + (size_t)wid * D + c * 16 + q4 * 4);
            ft[4 * q4] = f.x; ft[4 * q4 + 1] = f.y; ft[4 * q4 + 2] = f.z; ft[4 * q4 + 3] = f.w;
        }
        float r[16];
        const bf16x8* pv = reinterpret_cast<const bf16x8*>(ypin + (size_t)wid * 128 + c * 16);
#pragma unroll
        for (int hb = 0; hb < 2; ++hb) {
            bf16x8 prev = pv[hb];
            const __hip_bfloat162* h2 = reinterpret_cast<const __hip_bfloat162*>(&prev);
#pragma unroll
            for (int i = 0; i < 4; ++i) {
                float2 v2 = __bfloat1622float2(h2[i]);
                r[8 * hb + 2 * i]     = 0.25f * (ft[8 * hb + 2 * i] + v2.x + acc[8 * hb + 2 * i] * sp);
                r[8 * hb + 2 * i + 1] = 0.25f * (ft[8 * hb + 2 * i + 1] + v2.y + acc[8 * hb + 2 * i + 1] * sp);
            }
        }
        bf16x8* ov = reinterpret_cast<bf16x8*>(yp + (size_t)wid * 128 + c * 16);
        ov[0] = pack8(r);
        ov[1] = pack8(r + 8);
    }
}

// ---------------- GAT, 8 nodes/wave, 8 lanes/node over fp8 h (16B/lane), degree-binned ----
// Distributed attention weights: lane c computes p for edge c of each chunk; weights
// broadcast via width-8 shfl. Softmax denominator via width-8 reduce at the end.
// acc f[j] -> dim 16j+2c, f[j+8] -> dim 16j+2c+1 (gemm's permuted h8 layout).
__global__ __launch_bounds__(256) void gatw(const uint4* __restrict__ h16,
                                            const int* __restrict__ rowp,
                                            const int* __restrict__ csr,
                                            const int* __restrict__ perm,
                                            const float2* __restrict__ elsc,
                                            const float* __restrict__ er,
                                            const float* __restrict__ bias,
                                            float* __restrict__ out, int N) {
    int lane = threadIdx.x & 63;
    int g = lane >> 3, c = lane & 7;
    int widx = ((blockIdx.x * blockDim.x + threadIdx.x) >> 6) * 8 + g;
    if (widx >= N) return;
    int wid = perm[widx];
    int beg = rowp[wid], end = rowp[wid + 1];
    const char* xb = (const char*)h16;
    unsigned coff = (unsigned)(c << 4);
    float ern = er[wid];
    float psum = 0.f;
    fv2 acc2[8] = {{0.f, 0.f}, {0.f, 0.f}, {0.f, 0.f}, {0.f, 0.f},
                   {0.f, 0.f}, {0.f, 0.f}, {0.f, 0.f}, {0.f, 0.f}};
    int base = beg;
    int cur_s = (beg < end) ? csr[beg + min(c, end - beg - 1)] : 0;
    while (base < end) {
        int nb = base + 8;
        int next_s = 0;
        if (nb < end) next_s = csr[nb + min(c, end - nb - 1)];  // prefetch next chunk
        int kn = min(8, end - base);
        float2 es = elsc[cur_s];
        float t = es.x + ern;
        t = fmaxf(t, 0.2f * t);                 // leaky_relu (slope commutes with log2e)
        float p = (c < kn) ? fast_exp2(t) : 0.f;
        psum += p;
        float wv = p * es.y;                    // fold fp8 row scale into the weight
        uint4 v[8];
#pragma unroll
        for (int k = 0; k < 8; ++k) {
            int sk = __shfl(cur_s, k, 8);
            if (k < kn) v[k] = *(const uint4*)(xb + ((((unsigned)sk) << 7) | coff));
        }
#pragma unroll
        for (int k = 0; k < 8; ++k)
            if (k < kn) {
                float wk = __shfl(wv, k, 8);
                acc_fp8x16w(v[k], wk, acc2);
            }
        cur_s = next_s;
        base = nb;
    }
    // reduce softmax denominator across the 8 lanes of the group
    psum += __shfl_xor(psum, 1, 8);
    psum += __shfl_xor(psum, 2, 8);
    psum += __shfl_xor(psum, 4, 8);
    float inv = psum > 0.f ? 1.f / psum : 0.f;
    float zA[8], zB[8];
    float mx = -INFINITY;
#pragma unroll
    for (int j = 0; j < 8; ++j) {
        float2 b2 = *reinterpret_cast<const float2*>(bias + 16 * j + 2 * c);
        zA[j] = fmaxf(acc2[j >> 1][j & 1] * inv + b2.x, 0.f);               // f[j]
        zB[j] = fmaxf(acc2[(j + 8) >> 1][(j + 8) & 1] * inv + b2.y, 0.f);   // f[j+8]
        mx = fmaxf(mx, fmaxf(zA[j], zB[j]));
    }
    mx = fmaxf(mx, __shfl_xor(mx, 1, 8));
    mx = fmaxf(mx, __shfl_xor(mx, 2, 8));
    mx = fmaxf(mx, __shfl_xor(mx, 4, 8));
    float pz = 0.f;
#pragma unroll
    for (int j = 0; j < 8; ++j) pz += __expf(zA[j] - mx) + __expf(zB[j] - mx);
    pz += __shfl_xor(pz, 1, 8);
    pz += __shfl_xor(pz, 2, 8);
    pz += __shfl_xor(pz, 4, 8);
    float ls = logf(pz);
    float* op = out + (size_t)wid * D;
#pragma unroll
    for (int j = 0; j < 8; ++j) {
        float2 o2 = make_float2(zA[j] - mx - ls, zB[j] - mx - ls);
        *reinterpret_cast<float2*>(op + 16 * j + 2 * c) = o2;
    }
}

// ---------------- MFMA GEMM: h = y @ W (-> per-row-scaled fp8), el/er (log2e-scaled) --------
// h8 row layout (permuted): byte j of a row holds dim (j&7)*16 + (j>>3).
// elsc[row] = { el[row]*log2(e), rowmax/448 } ; er[row] *= log2(e).
__global__ __launch_bounds__(256) void gemm_mfma(const ushort* __restrict__ ybf,
                                                 const ushort* __restrict__ Wb,
                                                 const float* __restrict__ attnl,
                                                 const float* __restrict__ attnr,
                                                 unsigned char* __restrict__ h8,
                                                 float2* __restrict__ elsc,
                                                 float* __restrict__ er, int N) {
    __shared__ ushort Ws[16384];  // 32 KB packed W
    {
        const float4* srcv = reinterpret_cast<const float4*>(Wb);
        float4* dstv = reinterpret_cast<float4*>(Ws);
        for (int i = threadIdx.x; i < 2048; i += 256) dstv[i] = srcv[i];
    }
    __syncthreads();
    int wave = threadIdx.x >> 6, lane = threadIdx.x & 63;
    int base = blockIdx.x * 64 + wave * 16;
    if (base >= N) return;
    int col16 = lane & 15, rgrp = lane >> 4;

    int arow = base + col16;
    const bf16x8* yrow = reinterpret_cast<const bf16x8*>(ybf + (size_t)arow * 128);
    bf16x8 afrag[4];
#pragma unroll
    for (int t = 0; t < 4; ++t) afrag[t] = yrow[t * 4 + rgrp];

    const bf16x8* WsV = reinterpret_cast<const bf16x8*>(Ws);
    f32x4 acc[8];
#pragma unroll
    for (int c = 0; c < 8; ++c) acc[c] = (f32x4){0.f, 0.f, 0.f, 0.f};
#pragma unroll
    for (int c = 0; c < 8; ++c) {
#pragma unroll
        for (int t = 0; t < 4; ++t) {
            bf16x8 b = WsV[(c * 4 + t) * 64 + lane];
            acc[c] = __builtin_amdgcn_mfma_f32_16x16x32_bf16(afrag[t], b, acc[c], 0, 0, 0);
        }
    }

    float pl[4] = {0.f, 0.f, 0.f, 0.f}, pr[4] = {0.f, 0.f, 0.f, 0.f};
#pragma unroll
    for (int c = 0; c < 8; ++c) {
        float alc = attnl[c * 16 + col16];
        float arc = attnr[c * 16 + col16];
#pragma unroll
        for (int r = 0; r < 4; ++r) {
            pl[r] += acc[c][r] * alc;
            pr[r] += acc[c][r] * arc;
        }
    }
#pragma unroll
    for (int r = 0; r < 4; ++r) {
#pragma unroll
        for (int off = 8; off; off >>= 1) {
            pl[r] += __shfl_xor(pl[r], off);
            pr[r] += __shfl_xor(pr[r], off);
        }
    }

    // per-row absmax over the 16x128 tile rows (local 8 + butterfly over 16 lanes)
    float rmax[4];
#pragma unroll
    for (int r = 0; r < 4; ++r) {
        float m = 0.f;
#pragma unroll
        for (int c = 0; c < 8; ++c) m = fmaxf(m, fabsf(acc[c][r]));
#pragma unroll
        for (int off = 1; off < 16; off <<= 1) m = fmaxf(m, __shfl_xor(m, off));
        rmax[r] = fmaxf(m, 1e-20f);
    }

    // quantize: 8B chunk per lane per row (contiguous in the permuted layout)
#pragma unroll
    for (int r = 0; r < 4; ++r) {
        float iv = 448.f / rmax[r];
        float rr[8];
#pragma unroll
        for (int c = 0; c < 8; ++c) rr[c] = acc[c][r] * iv;
        uint2 pk = packfp8x8(rr);
        int row = base + rgrp * 4 + r;
        *reinterpret_cast<uint2*>(h8 + (size_t)row * 128 + col16 * 8) = pk;
    }

    const float LOG2E = 1.44269504088896340736f;
    if (col16 == 0) {
#pragma unroll
        for (int r = 0; r < 4; ++r) {
            int row = base + rgrp * 4 + r;
            elsc[row] = make_float2(pl[r] * LOG2E, rmax[r] * (1.f / 448.f));
            er[row] = pr[r] * LOG2E;
        }
    }
}

extern "C" void kernel_launch(void* const* d_in, const int* in_sizes, int n_in,
                              void* d_out, int out_size, void* d_ws, size_t ws_size,
                              hipStream_t stream) {
    const float* feats  = (const float*)d_in[0];
    const float* W      = (const float*)d_in[1];
    const float* attn_l = (const float*)d_in[2];
    const float* attn_r = (const float*)d_in[3];
    const float* bias   = (const float*)d_in[4];
    const int*   src    = (const int*)d_in[5];
    const int*   dst    = (const int*)d_in[6];
    int N = in_sizes[0] / D;
    int E = in_sizes[5];
    float* out = (float*)d_out;

    char* p = (char*)d_ws;
    auto alloc = [&](size_t bytes) {
        char* r = p;
        p += (bytes + 255) & ~size_t(255);
        return r;
    };
    int nblk = (N + 255) / 256;
    int*    deg_in = (int*)alloc((size_t)N * 4);
    int*    rowp   = (int*)alloc(((size_t)N + 1) * 4);
    int*    bsums  = (int*)alloc((size_t)SB * 4);
    int*    perm   = (int*)alloc((size_t)N * 4);
    int*    bins32 = (int*)alloc(32 * 4);
    int*    blkbase= (int*)alloc((size_t)nblk * 32 * 4);
    float*  n1     = (float*)alloc((size_t)N * 4);
    float*  n2     = (float*)alloc((size_t)N * 4);
    float*  er     = (float*)alloc((size_t)N * 4);
    float2* elsc   = (float2*)alloc((size_t)N * 8);
    int*    csr    = (int*)alloc((size_t)E * 4);
    ushort* Wb     = (ushort*)alloc((size_t)16384 * 2);
    // bf16 [N][128] buffers (12.8 MB each), allocated back-to-back so they can
    // alias the 2 x (GNUM x N-byte) u8 histograms (dead before first bf16 use)
    ushort* bufY1  = (ushort*)alloc((size_t)N * 128 * 2);  // Hs8 | yp (x1, x1+x2)
    ushort* bufY   = (ushort*)alloc((size_t)N * 128 * 2);  // Hd8 | y
    // fp8 [N][128] tables (6.4 MB each)
    uint4*  t0     = (uint4*)alloc((size_t)N * 8 * 16);    // x0s8, then h8
    uint4*  t1     = (uint4*)alloc((size_t)N * 8 * 16);    // nf8, then x1s8
    uint4*  t2     = (uint4*)alloc((size_t)N * 8 * 16);    // x2s8
    unsigned int* Hs = (unsigned int*)bufY1;
    unsigned int* Hd = (unsigned int*)bufY;

    const int tb = 256;
    // CSR build: fused dual histo -> fused colsum/scan/degbin -> row scan -> fill
    histo_both<<<GNUM, tb, 0, stream>>>(src, dst, Hs, Hd, bins32, E, N);
    col_both<<<nblk, tb, 0, stream>>>((const unsigned char*)Hs, (unsigned char*)Hd,
                                      deg_in, n1, n2, bins32, blkbase, N);
    scan32k<<<1, 64, 0, stream>>>(bins32);
    scatter_perm<<<nblk, tb, 0, stream>>>(deg_in, bins32, blkbase, perm, N);
    int nb = (N + SB - 1) / SB;
    scan_blocks<<<nb, SB, 0, stream>>>(deg_in, rowp, bsums, N);
    scan_sums<<<1, SB, 0, stream>>>(bsums, nb);
    scan_add<<<nb, SB, 0, stream>>>(rowp, bsums, N, E);
    fill_part<<<GNUM, tb, 0, stream>>>(src, dst, rowp, (const unsigned char*)Hd, csr, E, N);
    convert_W<<<8, tb, 0, stream>>>(W, Wb);
    convert_nf8<<<((size_t)N * 32 + tb - 1) / tb, tb, 0, stream>>>(feats, n2,
                                                                   (unsigned int*)t1, N);

    int wgrid8 = (N + 31) / 32;  // 4 waves/block x 8 nodes/wave = 32 nodes/block
    // rst: gather nf8(t1) -> x0s8(t0)
    spmmw<0><<<wgrid8, 256, 0, stream>>>(t1, nullptr, nullptr, rowp, csr, perm, n1, n2,
                                         nullptr, t0, N);
    // hop1: gather t0 -> yp=x1 (bufY1), x1s8(t1)
    spmmw<1><<<wgrid8, 256, 0, stream>>>(t0, nullptr, nullptr, rowp, csr, perm, n1, n2,
                                         bufY1, t1, N);
    // hop2: gather t1 -> yp+=x2, x2s8(t2)
    spmmw<2><<<wgrid8, 256, 0, stream>>>(t1, bufY1, nullptr, rowp, csr, perm, n1, n2,
                                         bufY1, t2, N);
    // fin: gather t2 -> y = 0.25*(feats + yp + x3) -> bufY
    spmmw<3><<<wgrid8, 256, 0, stream>>>(t2, bufY1, feats, rowp, csr, perm, n1, n2,
                                         bufY, nullptr, N);

    // h -> per-row-scaled fp8 into t0 (dead after hop1); el/er pre-scaled by log2(e)
    gemm_mfma<<<(N + 63) / 64, 256, 0, stream>>>(bufY, Wb, attn_l, attn_r,
                                                 (unsigned char*)t0, elsc, er, N);
    gatw<<<wgrid8, 256, 0, stream>>>((const uint4*)t0, rowp, csr, perm, elsc, er, bias,
                                     out, N);
}